// Round 7
// baseline (415.779 us; speedup 1.0000x reference)
//
#include <hip/hip_runtime.h>
#include <hip/hip_bf16.h>

// StreamingTransformerLayer on MI355X (gfx950).
// T=8192, D=512, DFF=2048. All-f32 in/out; internal GEMMs in bf16 MFMA.
// Round 7: attention restructured as two GEMM passes over a materialized,
// triangularly-packed S (bf16, L3-resident): qk_kernel (gemm body + mask +
// row-stats partials) -> stats_combine -> pv_kernel (gemm body, A = exp(S-m)
// reg-staged, split-K 4 chunks) -> pv_combine (sum * 1/l).

using bf16 = __hip_bfloat16;
typedef __attribute__((ext_vector_type(8))) short short8;  // 8 bf16 = 4 VGPR (MFMA frag)
typedef __attribute__((ext_vector_type(4))) float f32x4;

#define T_DIM 8192

#define AS1C(p) (const __attribute__((address_space(1))) void*)(p)
#define AS3P(p) (__attribute__((address_space(3))) void*)(p)
#define GLL16(src, dst) __builtin_amdgcn_global_load_lds(AS1C(src), AS3P(dst), 16, 0, 0)

static __device__ __forceinline__ short f2bfbits(float f) {
  bf16 b = __float2bfloat16(f);
  short s; __builtin_memcpy(&s, &b, 2); return s;
}
static __device__ __forceinline__ float bfbits2f(short s) {
  unsigned u = ((unsigned)(unsigned short)s) << 16;
  float f; __builtin_memcpy(&f, &u, 4); return f;
}

// ---------------- f32 -> bf16 convert ----------------
__global__ void cvt_kernel(const float* __restrict__ in, bf16* __restrict__ out, int n) {
  int i = blockIdx.x * 256 + threadIdx.x;
  if (i < n) out[i] = __float2bfloat16(in[i]);
}

// ---------------- LayerNorm: f32 [T,512] -> bf16 [T,512] ----------------
__global__ __launch_bounds__(256) void ln_kernel(
    const float* __restrict__ x, const float* __restrict__ g,
    const float* __restrict__ bb, bf16* __restrict__ h)
{
  const int row = blockIdx.x * 4 + (threadIdx.x >> 6);
  const int lane = threadIdx.x & 63;
  const float* xr = x + (size_t)row * 512 + lane * 8;
  f32x4 v0 = *(const f32x4*)xr;
  f32x4 v1 = *(const f32x4*)(xr + 4);
  float s = 0.f;
#pragma unroll
  for (int j = 0; j < 4; ++j) s += v0[j] + v1[j];
#pragma unroll
  for (int d = 1; d < 64; d <<= 1) s += __shfl_xor(s, d);
  const float mu = s * (1.f / 512.f);
  float vs = 0.f;
#pragma unroll
  for (int j = 0; j < 4; ++j) { float a = v0[j] - mu, b2 = v1[j] - mu; vs += a * a + b2 * b2; }
#pragma unroll
  for (int d = 1; d < 64; d <<= 1) vs += __shfl_xor(vs, d);
  const float rs = rsqrtf(vs * (1.f / 512.f) + 1e-5f);
  const f32x4 g0 = *(const f32x4*)(g + lane * 8);
  const f32x4 g1v = *(const f32x4*)(g + lane * 8 + 4);
  const f32x4 b0 = *(const f32x4*)(bb + lane * 8);
  const f32x4 b1v = *(const f32x4*)(bb + lane * 8 + 4);
  short8 ov;
#pragma unroll
  for (int j = 0; j < 4; ++j) {
    ov[j]     = f2bfbits((v0[j] - mu) * rs * g0[j] + b0[j]);
    ov[j + 4] = f2bfbits((v1[j] - mu) * rs * g1v[j] + b1v[j]);
  }
  *(short8*)(h + (size_t)row * 512 + lane * 8) = ov;
}

// ---------------- GEMM C = A * B^T (128x128 tile, BK=64, 4 waves) ----------
enum { MODE_BF16 = 0, MODE_GELU = 1, MODE_RESID = 2 };

static __device__ __forceinline__ float gelu_f(float x) {
  float x3 = x * x * x;
  float t = tanhf(0.7978845608028654f * (x + 0.044715f * x3));
  return 0.5f * x * (1.0f + t);
}

template <int MODE>
__global__ __launch_bounds__(256, 2) void gemm_bt(
    const bf16* __restrict__ A, const bf16* __restrict__ B,
    int M, int N, int K,
    bf16* __restrict__ Cb, float* __restrict__ Cf,
    const float* __restrict__ resid, const float* __restrict__ scale)
{
  __shared__ bf16 sA[128 * 64];
  __shared__ bf16 sB[128 * 64];
  const int tid = threadIdx.x;
  const int lane = tid & 63, wave = tid >> 6;
  const int bm = blockIdx.x, bn = blockIdx.y;
  const int wm = (wave & 1) * 64, wn = (wave >> 1) * 64;
  const int ln = lane & 15, lg = lane >> 4;
  f32x4 acc[4][4] = {};

  const int nkt = K >> 6;
  for (int kt = 0; kt < nkt; ++kt) {
    __syncthreads();
#pragma unroll
    for (int r = 0; r < 4; ++r) {
      const int s = r * 256 + tid;
      const int ks = s >> 9, rb = (s >> 6) & 7, l = s & 63;
      const bf16* srcA = A + (size_t)(bm * 128 + rb * 16 + (l & 15)) * K + kt * 64 + ks * 32 + (l >> 4) * 8;
      GLL16(srcA, sA + (size_t)(r * 256 + wave * 64) * 8);
      const bf16* srcB = B + (size_t)(bn * 128 + rb * 16 + (l & 15)) * K + kt * 64 + ks * 32 + (l >> 4) * 8;
      GLL16(srcB, sB + (size_t)(r * 256 + wave * 64) * 8);
    }
    __syncthreads();
#pragma unroll
    for (int ks = 0; ks < 2; ++ks) {
      short8 af[4], bfr[4];
#pragma unroll
      for (int mi = 0; mi < 4; ++mi)
        af[mi] = *(const short8*)(sA + (size_t)(ks * 512 + ((wm >> 4) + mi) * 64 + lane) * 8);
#pragma unroll
      for (int ni = 0; ni < 4; ++ni)
        bfr[ni] = *(const short8*)(sB + (size_t)(ks * 512 + ((wn >> 4) + ni) * 64 + lane) * 8);
#pragma unroll
      for (int mi = 0; mi < 4; ++mi)
#pragma unroll
        for (int ni = 0; ni < 4; ++ni)
          acc[mi][ni] = __builtin_amdgcn_mfma_f32_16x16x32_bf16(af[mi], bfr[ni], acc[mi][ni], 0, 0, 0);
    }
  }
#pragma unroll
  for (int mi = 0; mi < 4; ++mi) {
#pragma unroll
    for (int ni = 0; ni < 4; ++ni) {
#pragma unroll
      for (int r = 0; r < 4; ++r) {
        const int row = bm * 128 + wm + mi * 16 + lg * 4 + r;
        const int col = bn * 128 + wn + ni * 16 + ln;
        const size_t idx = (size_t)row * N + col;
        float v = acc[mi][ni][r];
        if constexpr (MODE == MODE_GELU) { Cb[idx] = __float2bfloat16(gelu_f(v)); }
        else if constexpr (MODE == MODE_RESID) { Cf[idx] = resid[idx] + scale[col] * v; }
        else { Cb[idx] = __float2bfloat16(v); }
      }
    }
  }
}

// ---------------- V transpose: proj[:,1024:1536] -> vT [512][T] ----------------
__global__ __launch_bounds__(256) void transpose_v(const bf16* __restrict__ proj, bf16* __restrict__ vT) {
  __shared__ bf16 tile[64][66];
  const int t0 = blockIdx.x * 64, d0 = blockIdx.y * 64;
  const int tid = threadIdx.x;
#pragma unroll
  for (int i = 0; i < 16; ++i) {
    const int lin = i * 256 + tid;
    const int r = lin >> 6, c = lin & 63;
    tile[r][c] = proj[(size_t)(t0 + r) * 1536 + 1024 + d0 + c];
  }
  __syncthreads();
#pragma unroll
  for (int i = 0; i < 16; ++i) {
    const int lin = i * 256 + tid;
    const int dy = lin >> 6, tx = lin & 63;
    vT[(size_t)(d0 + dy) * T_DIM + t0 + tx] = tile[tx][dy];
  }
}

// ---------------- QK^T GEMM: S = K @ Q^T (causal tiles), stats partials -----
// A = k rows (proj cols 512..1023, ld 1536), B = q rows (proj cols 0..511).
// Grid 64x64, early-exit bn>bm -> 2080 live tiles. S stored bf16 in
// triangular packing: tile (bm,bn) at (bm(bm+1)/2 + bn)*16384, local [128][128].
// Per-row per-64-col-half (max, expsum) partials -> Mp/Lp[row][128].
__global__ __launch_bounds__(256, 2) void qk_kernel(
    const bf16* __restrict__ proj, bf16* __restrict__ S,
    float* __restrict__ Mp, float* __restrict__ Lp)
{
  const int bm = blockIdx.x, bn = blockIdx.y;
  if (bn > bm) return;
  __shared__ bf16 sA[128 * 64];
  __shared__ bf16 sB[128 * 64];
  const int tid = threadIdx.x;
  const int lane = tid & 63, wave = tid >> 6;
  const int wm = (wave & 1) * 64, wn = (wave >> 1) * 64;
  const int ln = lane & 15, lg = lane >> 4;
  f32x4 acc[4][4] = {};

  for (int kt = 0; kt < 8; ++kt) {
    __syncthreads();
#pragma unroll
    for (int r = 0; r < 4; ++r) {
      const int s = r * 256 + tid;
      const int ks = s >> 9, rb = (s >> 6) & 7, l = s & 63;
      const bf16* srcA = proj + (size_t)(bm * 128 + rb * 16 + (l & 15)) * 1536 + 512 + kt * 64 + ks * 32 + (l >> 4) * 8;
      GLL16(srcA, sA + (size_t)(r * 256 + wave * 64) * 8);
      const bf16* srcB = proj + (size_t)(bn * 128 + rb * 16 + (l & 15)) * 1536 + kt * 64 + ks * 32 + (l >> 4) * 8;
      GLL16(srcB, sB + (size_t)(r * 256 + wave * 64) * 8);
    }
    __syncthreads();
#pragma unroll
    for (int ks = 0; ks < 2; ++ks) {
      short8 af[4], bfr[4];
#pragma unroll
      for (int mi = 0; mi < 4; ++mi)
        af[mi] = *(const short8*)(sA + (size_t)(ks * 512 + ((wm >> 4) + mi) * 64 + lane) * 8);
#pragma unroll
      for (int ni = 0; ni < 4; ++ni)
        bfr[ni] = *(const short8*)(sB + (size_t)(ks * 512 + ((wn >> 4) + ni) * 64 + lane) * 8);
#pragma unroll
      for (int mi = 0; mi < 4; ++mi)
#pragma unroll
        for (int ni = 0; ni < 4; ++ni)
          acc[mi][ni] = __builtin_amdgcn_mfma_f32_16x16x32_bf16(af[mi], bfr[ni], acc[mi][ni], 0, 0, 0);
    }
  }
  // ---- epilogue: causal mask, per-row stats (64-col half), S store ----
  float mx[4][4], sm[4][4];
#pragma unroll
  for (int mi = 0; mi < 4; ++mi)
#pragma unroll
    for (int r = 0; r < 4; ++r) {
      const int i = bm * 128 + wm + mi * 16 + lg * 4 + r;
      float vmax = -__builtin_inff();
#pragma unroll
      for (int ni = 0; ni < 4; ++ni) {
        const int j = bn * 128 + wn + ni * 16 + ln;
        if (j > i) acc[mi][ni][r] = -__builtin_inff();
        vmax = fmaxf(vmax, acc[mi][ni][r]);
      }
      mx[mi][r] = vmax;
    }
#pragma unroll
  for (int d = 1; d < 16; d <<= 1)
#pragma unroll
    for (int mi = 0; mi < 4; ++mi)
#pragma unroll
      for (int r = 0; r < 4; ++r) mx[mi][r] = fmaxf(mx[mi][r], __shfl_xor(mx[mi][r], d));
#pragma unroll
  for (int mi = 0; mi < 4; ++mi)
#pragma unroll
    for (int r = 0; r < 4; ++r) {
      mx[mi][r] = fmaxf(mx[mi][r], -1e30f);  // clamp: fully-masked half -> no NaN
      float sv = 0.f;
#pragma unroll
      for (int ni = 0; ni < 4; ++ni) sv += __expf(acc[mi][ni][r] - mx[mi][r]);
      sm[mi][r] = sv;
    }
#pragma unroll
  for (int d = 1; d < 16; d <<= 1)
#pragma unroll
    for (int mi = 0; mi < 4; ++mi)
#pragma unroll
      for (int r = 0; r < 4; ++r) sm[mi][r] += __shfl_xor(sm[mi][r], d);
  // store S (triangular-packed tile, bf16; masked entries are -inf)
  const size_t base = ((size_t)bm * (bm + 1) / 2 + bn) * 16384;
#pragma unroll
  for (int mi = 0; mi < 4; ++mi)
#pragma unroll
    for (int ni = 0; ni < 4; ++ni)
#pragma unroll
      for (int r = 0; r < 4; ++r)
        S[base + (size_t)(wm + mi * 16 + lg * 4 + r) * 128 + wn + ni * 16 + ln] =
            __float2bfloat16(acc[mi][ni][r]);
  // store stats partials (half h = wn>>6)
  if (ln == 0) {
    const int h = wn >> 6;
#pragma unroll
    for (int mi = 0; mi < 4; ++mi)
#pragma unroll
      for (int r = 0; r < 4; ++r) {
        const int i = bm * 128 + wm + mi * 16 + lg * 4 + r;
        Mp[(size_t)i * 128 + bn * 2 + h] = mx[mi][r];
        Lp[(size_t)i * 128 + bn * 2 + h] = sm[mi][r];
      }
  }
}

// ---------------- stats combine: m[i], 1/l[i] from partials ----------------
__global__ __launch_bounds__(256) void stats_combine(
    const float* __restrict__ Mp, const float* __restrict__ Lp,
    float* __restrict__ minv, float* __restrict__ linv)
{
  const int row = blockIdx.x * 4 + (threadIdx.x >> 6);
  const int lane = threadIdx.x & 63;
  const int cnt = 2 * (row >> 7) + 2;   // valid partials for this row
  float m0 = (lane < cnt)      ? Mp[(size_t)row * 128 + lane]      : -1e30f;
  float l0 = (lane < cnt)      ? Lp[(size_t)row * 128 + lane]      : 0.f;
  float m1 = (lane + 64 < cnt) ? Mp[(size_t)row * 128 + lane + 64] : -1e30f;
  float l1 = (lane + 64 < cnt) ? Lp[(size_t)row * 128 + lane + 64] : 0.f;
  float m = fmaxf(m0, m1);
#pragma unroll
  for (int d = 1; d < 64; d <<= 1) m = fmaxf(m, __shfl_xor(m, d));
  float ls = __expf(m0 - m) * l0 + __expf(m1 - m) * l1;
#pragma unroll
  for (int d = 1; d < 64; d <<= 1) ls += __shfl_xor(ls, d);
  if (lane == 0) { minv[row] = m; linv[row] = 1.0f / ls; }
}

// ---------------- PV GEMM: O-partials = exp(S - m) @ V (split-K 4) ---------
// A = P reg-staged (load S bf16, exp-transform, ds_write to the same LDS
// slots GLL16 would fill); B = vT (ld 8192) via GLL16. Grid (64 bm, 4 bn,
// 4 chunk); chunk covers [c*nk/4, (c+1)*nk/4) of nk = 2bm+2 K-steps.
__global__ __launch_bounds__(256, 2) void pv_kernel(
    const bf16* __restrict__ S, const bf16* __restrict__ vT,
    const float* __restrict__ minv, bf16* __restrict__ Opv)
{
  __shared__ bf16 sA[128 * 64];
  __shared__ bf16 sB[128 * 64];
  const int tid = threadIdx.x;
  const int lane = tid & 63, wave = tid >> 6;
  const int bm = blockIdx.x, bn = blockIdx.y, c = blockIdx.z;
  const int wm = (wave & 1) * 64, wn = (wave >> 1) * 64;
  const int ln = lane & 15, lg = lane >> 4;
  const int nk = 2 * bm + 2;
  const int k0 = c * nk / 4, k1 = (c + 1) * nk / 4;
  f32x4 acc[4][4] = {};

  // fixed staging rows per thread (depend only on r)
  float mrow[4];
  int arow[4];
#pragma unroll
  for (int r = 0; r < 4; ++r) {
    const int s = r * 256 + tid;
    arow[r] = ((s >> 6) & 7) * 16 + (s & 15);
    mrow[r] = minv[bm * 128 + arow[r]];
  }
  const size_t tribase = (size_t)bm * (bm + 1) / 2;

  for (int kt = k0; kt < k1; ++kt) {
    __syncthreads();
#pragma unroll
    for (int r = 0; r < 4; ++r) {
      const int s = r * 256 + tid;
      const int ks = s >> 9, rb = (s >> 6) & 7, l = s & 63;
      const int j = kt * 64 + ks * 32 + (l >> 4) * 8;   // 64-aligned range: one S tile
      // A: load S, transform exp(S - m[row]), write to the GLL16-equivalent slot
      const size_t saddr = (tribase + (j >> 7)) * 16384 + (size_t)arow[r] * 128 + (j & 127);
      const short8 sv = *(const short8*)(S + saddr);
      short8 pvv;
#pragma unroll
      for (int e = 0; e < 8; ++e) pvv[e] = f2bfbits(__expf(bfbits2f(sv[e]) - mrow[r]));
      *(short8*)(sA + (size_t)(r * 256 + tid) * 8) = pvv;
      // B: V columns via GLL16 from vT
      const bf16* srcB = vT + (size_t)(bn * 128 + rb * 16 + (l & 15)) * T_DIM + j;
      GLL16(srcB, sB + (size_t)(r * 256 + wave * 64) * 8);
    }
    __syncthreads();
#pragma unroll
    for (int ks = 0; ks < 2; ++ks) {
      short8 af[4], bfr[4];
#pragma unroll
      for (int mi = 0; mi < 4; ++mi)
        af[mi] = *(const short8*)(sA + (size_t)(ks * 512 + ((wm >> 4) + mi) * 64 + lane) * 8);
#pragma unroll
      for (int ni = 0; ni < 4; ++ni)
        bfr[ni] = *(const short8*)(sB + (size_t)(ks * 512 + ((wn >> 4) + ni) * 64 + lane) * 8);
#pragma unroll
      for (int mi = 0; mi < 4; ++mi)
#pragma unroll
        for (int ni = 0; ni < 4; ++ni)
          acc[mi][ni] = __builtin_amdgcn_mfma_f32_16x16x32_bf16(af[mi], bfr[ni], acc[mi][ni], 0, 0, 0);
    }
  }
  // store bf16 partials (every block writes its full tile; empty chunk -> 0)
#pragma unroll
  for (int mi = 0; mi < 4; ++mi)
#pragma unroll
    for (int ni = 0; ni < 4; ++ni)
#pragma unroll
      for (int r = 0; r < 4; ++r) {
        const int row = bm * 128 + wm + mi * 16 + lg * 4 + r;
        const int col = bn * 128 + wn + ni * 16 + ln;
        Opv[((size_t)c * T_DIM + row) * 512 + col] = __float2bfloat16(acc[mi][ni][r]);
      }
}

// ---------------- PV combine: o = (sum chunks) * 1/l ----------------
__global__ __launch_bounds__(256) void pv_combine(
    const bf16* __restrict__ Opv, const float* __restrict__ linv, bf16* __restrict__ o)
{
  const int row = blockIdx.x * 4 + (threadIdx.x >> 6);
  const int lane = threadIdx.x & 63;
  const float inv = linv[row];
  f32x4 a0 = {}, a1 = {};
#pragma unroll
  for (int c = 0; c < 4; ++c) {
    const short8 u = *(const short8*)(Opv + ((size_t)c * T_DIM + row) * 512 + lane * 8);
#pragma unroll
    for (int j = 0; j < 4; ++j) {
      a0[j] += bfbits2f(u[j]);
      a1[j] += bfbits2f(u[j + 4]);
    }
  }
  short8 ov;
#pragma unroll
  for (int j = 0; j < 4; ++j) {
    ov[j]     = f2bfbits(a0[j] * inv);
    ov[j + 4] = f2bfbits(a1[j] * inv);
  }
  *(short8*)(o + (size_t)row * 512 + lane * 8) = ov;
}

// ---------------- launch ----------------
extern "C" void kernel_launch(void* const* d_in, const int* in_sizes, int n_in,
                              void* d_out, int out_size, void* d_ws, size_t ws_size,
                              hipStream_t stream) {
  (void)in_sizes; (void)n_in; (void)out_size; (void)ws_size;
  const float* x    = (const float*)d_in[0];
  const float* Win  = (const float*)d_in[1];
  const float* Wout = (const float*)d_in[2];
  const float* W1   = (const float*)d_in[3];
  const float* W2   = (const float*)d_in[4];
  const float* g1   = (const float*)d_in[5];
  const float* b1   = (const float*)d_in[6];
  const float* g2   = (const float*)d_in[7];
  const float* b2   = (const float*)d_in[8];
  const float* ls1  = (const float*)d_in[9];
  const float* ls2  = (const float*)d_in[10];
  float* out = (float*)d_out;

  char* w = (char*)d_ws;
  size_t off = 0;
  auto alloc = [&](size_t bytes) -> char* {
    char* p = w + off; off += (bytes + 255) & ~(size_t)255; return p;
  };
  bf16* wWin  = (bf16*)alloc((size_t)1536 * 512 * 2);
  bf16* wWout = (bf16*)alloc((size_t)512 * 512 * 2);
  bf16* wW1   = (bf16*)alloc((size_t)2048 * 512 * 2);
  bf16* wW2   = (bf16*)alloc((size_t)512 * 2048 * 2);
  bf16* h     = (bf16*)alloc((size_t)T_DIM * 512 * 2);     // LN1 out; reused for LN2 out
  bf16* proj  = (bf16*)alloc((size_t)T_DIM * 1536 * 2);    // q|k|v
  bf16* vTb   = (bf16*)alloc((size_t)512 * T_DIM * 2);
  bf16* Sb    = (bf16*)alloc((size_t)2080 * 16384 * 2);    // 68MB triangular S
  float* Mp   = (float*)alloc((size_t)T_DIM * 128 * 4);    // 4MB stats partials
  float* Lp   = (float*)alloc((size_t)T_DIM * 128 * 4);    // 4MB
  float* minv = (float*)alloc((size_t)T_DIM * 4);
  float* linv = (float*)alloc((size_t)T_DIM * 4);
  bf16* Opv   = (bf16*)alloc((size_t)4 * T_DIM * 512 * 2); // 32MB PV partials
  bf16* f1 = proj;            // ffn1 out aliases proj (dead after attention)
  float* x1 = (float*)Sb;     // x1 (16MB) aliases Sb (dead after pv_kernel)
  bf16* o   = (bf16*)Mp;      // o (8MB) aliases Mp+Lp (dead after stats_combine)

  cvt_kernel<<<1536 * 512 / 256, 256, 0, stream>>>(Win, wWin, 1536 * 512);
  cvt_kernel<<<512 * 512 / 256, 256, 0, stream>>>(Wout, wWout, 512 * 512);
  cvt_kernel<<<2048 * 512 / 256, 256, 0, stream>>>(W1, wW1, 2048 * 512);
  cvt_kernel<<<512 * 2048 / 256, 256, 0, stream>>>(W2, wW2, 512 * 2048);

  ln_kernel<<<T_DIM / 4, 256, 0, stream>>>(x, g1, b1, h);
  gemm_bt<MODE_BF16><<<dim3(64, 12), 256, 0, stream>>>(h, wWin, 8192, 1536, 512, proj, nullptr, nullptr, nullptr);
  transpose_v<<<dim3(T_DIM / 64, 8), 256, 0, stream>>>(proj, vTb);
  qk_kernel<<<dim3(64, 64), 256, 0, stream>>>(proj, Sb, Mp, Lp);
  stats_combine<<<T_DIM / 4, 256, 0, stream>>>(Mp, Lp, minv, linv);
  pv_kernel<<<dim3(64, 4, 4), 256, 0, stream>>>(Sb, vTb, minv, Opv);
  pv_combine<<<T_DIM / 4, 256, 0, stream>>>(Opv, linv, o);
  gemm_bt<MODE_RESID><<<dim3(64, 4), 256, 0, stream>>>(o, wWout, 8192, 512, 512, nullptr, x1, x, ls1);
  ln_kernel<<<T_DIM / 4, 256, 0, stream>>>(x1, g2, b2, h);
  gemm_bt<MODE_GELU><<<dim3(64, 16), 256, 0, stream>>>(h, wW1, 8192, 2048, 512, f1, nullptr, nullptr, nullptr);
  gemm_bt<MODE_RESID><<<dim3(64, 4), 256, 0, stream>>>(f1, wW2, 8192, 512, 2048, nullptr, out, x1, ls2);
}